// Round 1
// baseline (517.932 us; speedup 1.0000x reference)
//
#include <hip/hip_runtime.h>
#include <stdint.h>

#define NB   256          // batch
#define HH   512
#define WW   512
#define HWSZ (HH * WW)    // 262144 floats per batch plane
#define SPLIT 16          // blocks per batch in pass 1
#define THREADS 256

// d_ws layout: [0, NB*8) packed argmax keys (u64); [NB*8, NB*8+8) double accumulator.

// Pass 1: per-batch first-argmax of target (packed u64 atomicMax) + unweighted sum of diff^2.
__global__ __launch_bounds__(THREADS) void pass1_kernel(
    const float* __restrict__ outp, const float* __restrict__ tgt,
    unsigned long long* __restrict__ keys, double* __restrict__ acc) {
  const int blk   = blockIdx.x;
  const int b     = blk / SPLIT;
  const int chunk = blk % SPLIT;
  const int f4_per_block = HWSZ / 4 / SPLIT;           // 4096 float4 per block
  const size_t base4 = (size_t)b * (HWSZ / 4) + (size_t)chunk * f4_per_block;
  const float4* o4 = (const float4*)outp + base4;
  const float4* t4 = (const float4*)tgt  + base4;

  const int t = threadIdx.x;
  float    sum     = 0.0f;
  float    bestv   = -1.0f;          // always overwritten (targets are >= 0)
  unsigned bestidx = 0u;

  #pragma unroll
  for (int i = 0; i < f4_per_block / THREADS; ++i) {   // 16 iters, coalesced
    const int p = i * THREADS + t;                     // monotonically increasing per thread
    const float4 ov = o4[p];
    const float4 tv = t4[p];
    const float d0 = ov.x - tv.x, d1 = ov.y - tv.y;
    const float d2 = ov.z - tv.z, d3 = ov.w - tv.w;
    sum += d0 * d0 + d1 * d1 + d2 * d2 + d3 * d3;
    const unsigned fi = (unsigned)((chunk * f4_per_block + p) * 4);
    // strict '>' keeps FIRST max within this thread (indices increase with i)
    if (tv.x > bestv) { bestv = tv.x; bestidx = fi;     }
    if (tv.y > bestv) { bestv = tv.y; bestidx = fi + 1; }
    if (tv.z > bestv) { bestv = tv.z; bestidx = fi + 2; }
    if (tv.w > bestv) { bestv = tv.w; bestidx = fi + 3; }
  }

  // pack: high 32 = float bits (nonneg => monotonic), low 32 = ~idx (max key => min idx)
  unsigned long long key =
      ((unsigned long long)__float_as_uint(bestv) << 32) | (unsigned long long)(~bestidx);

  // wave-64 reduce
  const int lane = t & 63, wave = t >> 6;
  #pragma unroll
  for (int off = 32; off > 0; off >>= 1) {
    unsigned long long ok = __shfl_down(key, off, 64);
    if (ok > key) key = ok;
    sum += __shfl_down(sum, off, 64);
  }
  __shared__ unsigned long long skey[THREADS / 64];
  __shared__ float              ssum[THREADS / 64];
  if (lane == 0) { skey[wave] = key; ssum[wave] = sum; }
  __syncthreads();
  if (t == 0) {
    unsigned long long k = skey[0];
    float s = ssum[0];
    #pragma unroll
    for (int i = 1; i < THREADS / 64; ++i) {
      if (skey[i] > k) k = skey[i];
      s += ssum[i];
    }
    atomicMax(&keys[b], k);
    atomicAdd(acc, (double)s);
  }
}

// Pass 2: correction sum over the penalty window: (vh*vw - 1) * diff^2.
__global__ __launch_bounds__(THREADS) void pass2_kernel(
    const float* __restrict__ outp, const float* __restrict__ tgt,
    const unsigned long long* __restrict__ keys, double* __restrict__ acc) {
  const int b = blockIdx.x;
  const unsigned long long key = keys[b];
  const float maxv = __uint_as_float((unsigned)(key >> 32));
  if (maxv < 0.5f) return;                       // block-uniform: safe before barriers
  const unsigned idx = ~(unsigned)(key & 0xFFFFFFFFull);
  const int ph = (int)(idx / WW), pw = (int)(idx % WW);
  const int dh = HH / 16, dw = WW / 16;          // 32, 32
  const int top  = max(ph - dh, 0), bot   = min(ph + dh, HH);
  const int left = max(pw - dw, 0), right = min(pw + dw, WW);
  const int Lh = bot - top, Lw = right - left;   // each in [32, 64]
  const float nh = (float)max((Lh + 1) / 2 - 1, 1);   // denom = max(n-1, 1)
  const float nw = (float)max((Lw + 1) / 2 - 1, 1);
  const float* ob = outp + (size_t)b * HWSZ;
  const float* tb = tgt  + (size_t)b * HWSZ;

  float sum = 0.0f;
  const int n_elems = Lh * Lw;
  for (int j = threadIdx.x; j < n_elems; j += THREADS) {
    const int r = j / Lw, c = j % Lw;
    const int kr = min(r, Lh - 1 - r), kc = min(c, Lw - 1 - c);
    const float vh = 1.0f + 9.0f * (float)kr / nh;
    const float vw = 1.0f + 9.0f * (float)kc / nw;
    const int row = top + r, col = left + c;
    const float d = ob[row * WW + col] - tb[row * WW + col];
    sum += (vh * vw - 1.0f) * d * d;
  }

  const int lane = threadIdx.x & 63, wave = threadIdx.x >> 6;
  #pragma unroll
  for (int off = 32; off > 0; off >>= 1) sum += __shfl_down(sum, off, 64);
  __shared__ float ssum[THREADS / 64];
  if (lane == 0) ssum[wave] = sum;
  __syncthreads();
  if (threadIdx.x == 0) {
    float s = 0.0f;
    #pragma unroll
    for (int i = 0; i < THREADS / 64; ++i) s += ssum[i];
    atomicAdd(acc, (double)s);
  }
}

__global__ void finalize_kernel(const double* __restrict__ acc, float* __restrict__ out) {
  out[0] = (float)(acc[0] / (double)((size_t)NB * HWSZ));
}

extern "C" void kernel_launch(void* const* d_in, const int* in_sizes, int n_in,
                              void* d_out, int out_size, void* d_ws, size_t ws_size,
                              hipStream_t stream) {
  const float* outp = (const float*)d_in[0];   // "output"
  const float* tgt  = (const float*)d_in[1];   // "target"
  unsigned long long* keys = (unsigned long long*)d_ws;
  double* acc = (double*)((char*)d_ws + NB * sizeof(unsigned long long));

  // ws is poisoned 0xAA before every call — zero keys + accumulator.
  hipMemsetAsync(d_ws, 0, NB * sizeof(unsigned long long) + sizeof(double), stream);

  pass1_kernel<<<NB * SPLIT, THREADS, 0, stream>>>(outp, tgt, keys, acc);
  pass2_kernel<<<NB, THREADS, 0, stream>>>(outp, tgt, keys, acc);
  finalize_kernel<<<1, 1, 0, stream>>>(acc, (float*)d_out);
}